// Round 4
// baseline (192.804 us; speedup 1.0000x reference)
//
#include <hip/hip_runtime.h>

// UFO linear attention, MI355X (gfx950). B=8, N=4096, C=512, H=8, DK=DV=64.
//
// R7: de-risked rebuild of R6 (which produced NaN). Same structural idea:
// both GEMM operands staged via global_load_lds (A as raw fp32, swizzled
// pre-computed per-lane SOURCE address + linear LDS dest; B bf16 same
// pattern, proven in R5), m97 single-buffered skeleton. Changes vs R6:
//   - conversion fp32->bf16 on fragment read uses the PROVEN f2b
//     bit-twiddle (R6's v_cvt_pk_bf16_f32 inline asm was unproven).
//   - ALL synchronization is plain __syncthreads() (compiler-emitted
//     vmcnt/lgkm drain + barrier) -- no hand-rolled waitcnt/raw barriers.
//   - LDS arrays __align__(16).
// LDS 48 KB (proj) / 32 KB (final) -> 3 blocks/CU.

typedef __attribute__((ext_vector_type(4))) float f32x4;
typedef __attribute__((ext_vector_type(8))) short s16x8;
typedef __attribute__((ext_vector_type(4))) unsigned short u16x4;
typedef __attribute__((ext_vector_type(8))) unsigned short u16x8;

#define DEVFN __device__ __forceinline__

DEVFN unsigned short f2b(float f) {  // fp32 -> bf16 RNE
  union { float f; unsigned u; } un; un.f = f;
  unsigned r = un.u + 0x7fffu + ((un.u >> 16) & 1u);
  return (unsigned short)(r >> 16);
}
DEVFN float b2f(unsigned short us) {
  union { unsigned u; float f; } un; un.u = ((unsigned)us) << 16;
  return un.f;
}

// async global->LDS, 16 B per lane; lds dest = wave-uniform base + lane*16
DEVFN void gl_lds16(const void* g, void* l) {
  __builtin_amdgcn_global_load_lds(
      (const __attribute__((address_space(1))) unsigned*)g,
      (__attribute__((address_space(3))) unsigned*)l, 16, 0, 0);
}

// ---------------------------------------------------------------------------
// Core GEMM: C[m][n] = sum_k A[m][k]*Bt[n][k] + bias[n]; optional fused
// head-norm. M = grid, N = K = 512. 128x128 tile, BK=64, 4 waves.
// m97 skeleton: STAGE(t); sync; COMPUTE(t); sync; STAGE(t+1); ...
// ---------------------------------------------------------------------------
template <bool AF32, typename CT>
DEVFN void gemm_core(const void* Ain, const unsigned short* Bt,
                     const float* bias, CT* C, bool qnorm, const float* gamma,
                     int bx, int by) {
  constexpr int KK = 512, NN = 512;
  __shared__ __align__(16) char AsLDS[AF32 ? 32768 : 16384];  // swizzled
  __shared__ __align__(16) char BsLDS[16384];                 // swizzled
  const int tid = threadIdx.x, lane = tid & 63, wid = tid >> 6;
  const int wm = (wid >> 1) * 64, wn = (wid & 1) * 64;
  const int r = lane & 15, g = lane >> 4;

  // ---- pre-swizzled per-lane staging sources (linear LDS dest) ----
  // B (bf16, 1024 B/row): chunk c = wid*4+q covers rows [c*8, c*8+8);
  // lane l -> row c*8 + (l>>3), source 16B slot (l&7) ^ (l>>3)   [= row&7].
  const char* Bsrc = (const char*)Bt +
      (long)(by * 128 + wid * 32 + (lane >> 3)) * 1024 +
      (((lane & 7) ^ (lane >> 3)) * 16);
  // A fp32 (2048 B/row): chunk c = wid*8+q covers rows [c*4, c*4+4);
  // lane l -> row c*4 + (l>>4), source slot (l&15) ^ (row&7),
  // row&7 = (q&1)*4 + (l>>4).
  const char* Asrc_e = nullptr;  // q even
  const char* Asrc_o = nullptr;  // q odd
  if constexpr (AF32) {
    const char* ab = (const char*)Ain +
        (long)(bx * 128 + wid * 32 + (lane >> 4)) * 2048;
    Asrc_e = ab + (((lane & 15) ^ (lane >> 4)) * 16);
    Asrc_o = ab + (((lane & 15) ^ (4 + (lane >> 4))) * 16);
  } else {
    Asrc_e = (const char*)Ain +
        (long)(bx * 128 + wid * 32 + (lane >> 3)) * 1024 +
        (((lane & 7) ^ (lane >> 3)) * 16);
  }

  f32x4 acc[4][4] = {};

#define STAGE(KT)                                                              \
  {                                                                            \
    if constexpr (AF32) {                                                      \
      _Pragma("unroll") for (int q = 0; q < 8; ++q)                            \
          gl_lds16((q & 1 ? Asrc_o : Asrc_e) + q * 8192 + (KT)*256,            \
                   AsLDS + (wid * 8 + q) * 1024);                              \
    } else {                                                                   \
      _Pragma("unroll") for (int q = 0; q < 4; ++q)                            \
          gl_lds16(Asrc_e + q * 8192 + (KT)*128,                               \
                   AsLDS + wid * 4096 + q * 1024);                             \
    }                                                                          \
    _Pragma("unroll") for (int q = 0; q < 4; ++q)                              \
        gl_lds16(Bsrc + q * 8192 + (KT)*128,                                   \
                 BsLDS + wid * 4096 + q * 1024);                               \
  }

#define COMPUTE                                                                \
  {                                                                            \
    _Pragma("unroll") for (int ks = 0; ks < 2; ++ks) {                         \
      s16x8 a[4], b[4];                                                        \
      const int kb = ks * 64 + g * 16;                                         \
      _Pragma("unroll") for (int i = 0; i < 4; ++i) {                          \
        int ar = wm + i * 16 + r;                                              \
        if constexpr (AF32) {                                                  \
          const int kc = ks * 128 + g * 32;                                    \
          f32x4 alo = *reinterpret_cast<const f32x4*>(                         \
              AsLDS + ar * 256 + (kc ^ ((ar & 7) << 4)));                      \
          f32x4 ahi = *reinterpret_cast<const f32x4*>(                         \
              AsLDS + ar * 256 + ((kc + 16) ^ ((ar & 7) << 4)));               \
          s16x8 av;                                                            \
          av[0] = (short)f2b(alo[0]); av[1] = (short)f2b(alo[1]);              \
          av[2] = (short)f2b(alo[2]); av[3] = (short)f2b(alo[3]);              \
          av[4] = (short)f2b(ahi[0]); av[5] = (short)f2b(ahi[1]);              \
          av[6] = (short)f2b(ahi[2]); av[7] = (short)f2b(ahi[3]);              \
          a[i] = av;                                                           \
        } else {                                                               \
          a[i] = *reinterpret_cast<const s16x8*>(                              \
              AsLDS + ar * 128 + (kb ^ ((ar & 7) << 4)));                      \
        }                                                                      \
        int br = wn + i * 16 + r;                                              \
        b[i] = *reinterpret_cast<const s16x8*>(                                \
            BsLDS + br * 128 + (kb ^ ((br & 7) << 4)));                        \
      }                                                                        \
      _Pragma("unroll") for (int i = 0; i < 4; ++i)                            \
          _Pragma("unroll") for (int j = 0; j < 4; ++j) acc[i][j] =            \
          __builtin_amdgcn_mfma_f32_16x16x32_bf16(a[i], b[j], acc[i][j], 0,    \
                                                  0, 0);                       \
    }                                                                          \
  }

#define SYNC __syncthreads();

  STAGE(0) SYNC
  COMPUTE SYNC STAGE(1) SYNC
  COMPUTE SYNC STAGE(2) SYNC
  COMPUTE SYNC STAGE(3) SYNC
  COMPUTE SYNC STAGE(4) SYNC
  COMPUTE SYNC STAGE(5) SYNC
  COMPUTE SYNC STAGE(6) SYNC
  COMPUTE SYNC STAGE(7) SYNC
  COMPUTE

#undef STAGE
#undef COMPUTE
#undef SYNC

  // ---- epilogue (C/D layout: col=lane&15, row=(lane>>4)*4+ii) ----
  const int crow0 = bx * 128 + wm + g * 4;
  const int ccol0 = by * 128 + wn + r;
#pragma unroll
  for (int j = 0; j < 4; ++j) {
    float bv = bias[ccol0 + j * 16];
#pragma unroll
    for (int i = 0; i < 4; ++i)
#pragma unroll
      for (int ii = 0; ii < 4; ++ii) acc[i][j][ii] += bv;
  }
  if (qnorm) {  // wave's 64 cols == one head; L2-norm over them per row
    const int h = (by * 128 + wn) >> 6;
    const float gam = gamma[h];
#pragma unroll
    for (int i = 0; i < 4; ++i)
#pragma unroll
      for (int ii = 0; ii < 4; ++ii) {
        float s = 0.f;
#pragma unroll
        for (int j = 0; j < 4; ++j) s += acc[i][j][ii] * acc[i][j][ii];
        s += __shfl_xor(s, 1);
        s += __shfl_xor(s, 2);
        s += __shfl_xor(s, 4);
        s += __shfl_xor(s, 8);
        float sc = gam / sqrtf(s);
#pragma unroll
        for (int j = 0; j < 4; ++j) acc[i][j][ii] *= sc;
      }
  }
#pragma unroll
  for (int i = 0; i < 4; ++i)
#pragma unroll
    for (int j = 0; j < 4; ++j)
#pragma unroll
      for (int ii = 0; ii < 4; ++ii) {
        long row = crow0 + i * 16 + ii;
        int col = ccol0 + j * 16;
        if constexpr (sizeof(CT) == 2)
          C[row * NN + col] = f2b(acc[i][j][ii]);
        else
          C[row * NN + col] = acc[i][j][ii];
      }
}

// y-inner + XCD-chunked bijective swizzle; NWG must be a multiple of 32.
DEVFN void swz_xy(int bid, int nwg, int& bx, int& by) {
  int s = (bid & 7) * (nwg >> 3) + (bid >> 3);
  bx = s >> 2;
  by = s & 3;
}

__global__ __launch_bounds__(256, 3)
void proj_qkv(const float* __restrict__ Aq, const float* __restrict__ Ak,
              const float* __restrict__ Av, const unsigned short* __restrict__ Bq,
              const unsigned short* __restrict__ Bk, const unsigned short* __restrict__ Bv,
              const float* __restrict__ bq, const float* __restrict__ bk,
              const float* __restrict__ bv, unsigned short* __restrict__ Cq,
              unsigned short* __restrict__ Ck, unsigned short* __restrict__ Cv,
              const float* __restrict__ gamma) {
  const int z = blockIdx.z;
  const float* A = z == 0 ? Aq : (z == 1 ? Ak : Av);
  const unsigned short* B = z == 0 ? Bq : (z == 1 ? Bk : Bv);
  const float* bias = z == 0 ? bq : (z == 1 ? bk : bv);
  unsigned short* C = z == 0 ? Cq : (z == 1 ? Ck : Cv);
  int bx, by;
  swz_xy(blockIdx.x, 1024, bx, by);
  gemm_core<true, unsigned short>(A, B, bias, C, z == 0, gamma, bx, by);
}

__global__ __launch_bounds__(256, 3)
void gemm_final(const unsigned short* __restrict__ q, const unsigned short* __restrict__ Mt,
                const float* __restrict__ bo, float* __restrict__ out) {
  const int zb = blockIdx.z;
  int bx, by;
  swz_xy(blockIdx.x, 128, bx, by);
  gemm_core<false, float>(q + (long)zb * 2097152, Mt + (long)zb * 262144, bo,
                          out + (long)zb * 2097152, false, nullptr, bx, by);
}

// ---------------------------------------------------------------------------
// kv partials: part[chunk][bh][dk][dv] = sum over 256 n of k outer v
// ---------------------------------------------------------------------------
#define NCHUNK 16
__global__ __launch_bounds__(256, 2)
void kv_partial(const unsigned short* __restrict__ kq,
                const unsigned short* __restrict__ vq,
                float* __restrict__ part) {
  const int tid = threadIdx.x;
  const int chunk = blockIdx.x;
  const int bh = blockIdx.y;
  const int b = bh >> 3, h = bh & 7;
  __shared__ float ks[32][64];
  __shared__ float vs[32][64];
  const int dk0 = (tid & 15) * 4;
  const int dv0 = (tid >> 4) * 4;
  float acc[4][4] = {};
  const long nbase = (long)b * 4096 + chunk * 256;

  for (int sub = 0; sub < 8; ++sub) {
    long n0 = nbase + sub * 32;
#pragma unroll
    for (int i = 0; i < 2; ++i) {
      int e = i * 256 + tid;
      int row = e >> 4, c4 = e & 15;
      long gofs = (n0 + row) * 512 + h * 64 + c4 * 4;
      u16x4 kk = *reinterpret_cast<const u16x4*>(kq + gofs);
      u16x4 vv = *reinterpret_cast<const u16x4*>(vq + gofs);
      f32x4 kf = {b2f(kk[0]), b2f(kk[1]), b2f(kk[2]), b2f(kk[3])};
      f32x4 vf = {b2f(vv[0]), b2f(vv[1]), b2f(vv[2]), b2f(vv[3])};
      *reinterpret_cast<f32x4*>(&ks[row][c4 * 4]) = kf;
      *reinterpret_cast<f32x4*>(&vs[row][c4 * 4]) = vf;
    }
    __syncthreads();
#pragma unroll 4
    for (int n = 0; n < 32; ++n) {
      f32x4 kk = *reinterpret_cast<const f32x4*>(&ks[n][dk0]);
      f32x4 vv = *reinterpret_cast<const f32x4*>(&vs[n][dv0]);
#pragma unroll
      for (int a = 0; a < 4; ++a)
#pragma unroll
        for (int c = 0; c < 4; ++c)
          acc[a][c] += kk[a] * vv[c];
    }
    __syncthreads();
  }
  float* pg = part + ((long)chunk * 64 + bh) * 4096;
#pragma unroll
  for (int a = 0; a < 4; ++a) {
    f32x4 o = {acc[a][0], acc[a][1], acc[a][2], acc[a][3]};
    *reinterpret_cast<f32x4*>(pg + (dk0 + a) * 64 + dv0) = o;
  }
}

// reduce partials + L2-norm rows (over dv) * gamma -> kvn bf16 [bh][64][64]
__global__ __launch_bounds__(256)
void kv_normN(const float* __restrict__ part, const float* __restrict__ gamma,
              unsigned short* __restrict__ kvn) {
  const int bh = blockIdx.x, h = bh & 7;
  const int tid = threadIdx.x;
  __shared__ float kvs[4096];
  __shared__ float scale[64];
#pragma unroll
  for (int i = 0; i < 4; ++i) {
    int e4 = i * 256 + tid;
    const float* p = part + (long)bh * 4096 + e4 * 4;
    f32x4 s = {0.f, 0.f, 0.f, 0.f};
#pragma unroll
    for (int c = 0; c < NCHUNK; ++c) {
      f32x4 v = *reinterpret_cast<const f32x4*>(p + (long)c * 64 * 4096);
      s += v;
    }
    *reinterpret_cast<f32x4*>(kvs + e4 * 4) = s;
  }
  __syncthreads();
  if (tid < 64) {
    float s = 0.f;
    for (int dv = 0; dv < 64; ++dv) { float x = kvs[tid * 64 + dv]; s += x * x; }
    scale[tid] = gamma[h] / sqrtf(s);
  }
  __syncthreads();
#pragma unroll
  for (int i = 0; i < 4; ++i) {
    int e4 = i * 256 + tid;
    float sc = scale[e4 >> 4];
    f32x4 v = *reinterpret_cast<const f32x4*>(kvs + e4 * 4);
    u16x4 o = {f2b(v[0] * sc), f2b(v[1] * sc), f2b(v[2] * sc), f2b(v[3] * sc)};
    *reinterpret_cast<u16x4*>(kvn + (long)bh * 4096 + e4 * 4) = o;
  }
}

// Mt[b][c][h*64+dk] = sum_dv Wo[c][h*64+dv] * kvn[b,h][dk][dv]
__global__ __launch_bounds__(64)
void mt_kernel(const unsigned short* __restrict__ Wo_b,
               const unsigned short* __restrict__ kvn,
               unsigned short* __restrict__ Mt) {
  const int bid = blockIdx.x;
  const int bh = bid >> 2, seg = bid & 3;
  const int b = bh >> 3, h = bh & 7;
  const int lane = threadIdx.x;
  const int r = lane & 15, g = lane >> 4;
  f32x4 acc[8][4] = {};
  s16x8 bf[2][4];
#pragma unroll
  for (int ks = 0; ks < 2; ++ks)
#pragma unroll
    for (int j = 0; j < 4; ++j)
      bf[ks][j] = *reinterpret_cast<const s16x8*>(
          kvn + (long)bh * 4096 + (j * 16 + r) * 64 + ks * 32 + g * 8);
#pragma unroll
  for (int ks = 0; ks < 2; ++ks)
#pragma unroll
    for (int i = 0; i < 8; ++i) {
      s16x8 af = *reinterpret_cast<const s16x8*>(
          Wo_b + (long)(seg * 128 + i * 16 + r) * 512 + h * 64 + ks * 32 + g * 8);
#pragma unroll
      for (int j = 0; j < 4; ++j)
        acc[i][j] = __builtin_amdgcn_mfma_f32_16x16x32_bf16(af, bf[ks][j], acc[i][j], 0, 0, 0);
    }
#pragma unroll
  for (int i = 0; i < 8; ++i)
#pragma unroll
    for (int j = 0; j < 4; ++j)
#pragma unroll
      for (int ii = 0; ii < 4; ++ii) {
        int c = seg * 128 + i * 16 + g * 4 + ii;
        int dk = j * 16 + r;
        Mt[(long)b * 262144 + (long)c * 512 + h * 64 + dk] = f2b(acc[i][j][ii]);
      }
}

__global__ void cast4(const float* __restrict__ a0, const float* __restrict__ a1,
                      const float* __restrict__ a2, const float* __restrict__ a3,
                      unsigned short* __restrict__ o0, unsigned short* __restrict__ o1,
                      unsigned short* __restrict__ o2, unsigned short* __restrict__ o3) {
  const int y = blockIdx.y;
  const float* in = y == 0 ? a0 : (y == 1 ? a1 : (y == 2 ? a2 : a3));
  unsigned short* out = y == 0 ? o0 : (y == 1 ? o1 : (y == 2 ? o2 : o3));
  int i = blockIdx.x * 256 + threadIdx.x;
  f32x4 v = reinterpret_cast<const f32x4*>(in)[i];
  reinterpret_cast<u16x4*>(out)[i] = u16x4{f2b(v[0]), f2b(v[1]), f2b(v[2]), f2b(v[3])};
}

// ---------------------------------------------------------------------------
extern "C" void kernel_launch(void* const* d_in, const int* in_sizes, int n_in,
                              void* d_out, int out_size, void* d_ws, size_t ws_size,
                              hipStream_t stream) {
  const float* queries = (const float*)d_in[0];
  const float* keys    = (const float*)d_in[1];
  const float* values  = (const float*)d_in[2];
  const float* Wq = (const float*)d_in[3];
  const float* bq = (const float*)d_in[4];
  const float* Wk = (const float*)d_in[5];
  const float* bk = (const float*)d_in[6];
  const float* Wv = (const float*)d_in[7];
  const float* bv = (const float*)d_in[8];
  const float* Wo = (const float*)d_in[9];
  const float* bo = (const float*)d_in[10];
  const float* gamma = (const float*)d_in[11];

  unsigned short* Wq_b = (unsigned short*)d_ws;            // 512 KB each
  unsigned short* Wk_b = Wq_b + 262144;
  unsigned short* Wv_b = Wk_b + 262144;
  unsigned short* Wo_b = Wv_b + 262144;
  unsigned short* q_b  = Wo_b + 262144;                    // 32 MB (holds q_n)
  unsigned short* kvn  = q_b + 16777216;                   // 512 KB
  float* part = (float*)(kvn + 262144);                    // 16 MB
  unsigned short* Mt = (unsigned short*)part;              // 4 MB (part dead by then)
  unsigned short* k_b = (unsigned short*)d_out;            // d_out scratch
  unsigned short* v_b = k_b + 16777216;
  float* out = (float*)d_out;

  cast4<<<dim3(256, 4), 256, 0, stream>>>(Wq, Wk, Wv, Wo, Wq_b, Wk_b, Wv_b, Wo_b);

  proj_qkv<<<dim3(1024, 1, 3), 256, 0, stream>>>(
      queries, keys, values, Wq_b, Wk_b, Wv_b, bq, bk, bv, q_b, k_b, v_b, gamma);

  kv_partial<<<dim3(NCHUNK, 64), 256, 0, stream>>>(k_b, v_b, part);
  kv_normN<<<64, 256, 0, stream>>>(part, gamma, kvn);
  mt_kernel<<<256, 64, 0, stream>>>(Wo_b, kvn, Mt);

  gemm_final<<<dim3(128, 1, 8), 256, 0, stream>>>(q_b, Mt, bo, out);
}